// Round 1
// baseline (12195.158 us; speedup 1.0000x reference)
//
#include <hip/hip_runtime.h>
#include <math.h>

// ResidualVQ fused forward, MI355X (gfx950).
// Full fp64 chain: codes must match the numpy reference's argmin exactly
// (threshold 20.48 on codes => no flips allowed; fp32 chain risks ~1-5
// near-tie flips vs an fp64 reference across 262144 decisions).
//
// Layout: 2048 blocks x 256 threads; 16 tokens/block.
// thread t: group g = t>>5 (8 groups of 32 lanes), lane m = t&31.
// group g owns tokens tok0 = blk*16 + 2g + {0,1}; lane m owns d = m + 32j.
// Residual: double res[2][32] in VGPRs for all 8 layers (no HBM round-trip).

#define NTHREADS 256

__global__ void __launch_bounds__(64) rvq_init(float* p) {
    if (threadIdx.x < 3) p[threadIdx.x] = 0.0f;
}

__global__ void __launch_bounds__(NTHREADS, 2) rvq_main(
    const float* __restrict__ z_e, const float* __restrict__ Wd,
    const float* __restrict__ bd,  const float* __restrict__ cb,
    const float* __restrict__ Wu,  const float* __restrict__ bu,
    float* __restrict__ out0, float* __restrict__ out1,
    float* __restrict__ lossp)
{
    // 4608 doubles = 36864 B, reused as:
    //  phase A: WdT staged fp32 [512][18] (then fp64 reduce buf [32][130])
    //  phase B: cbn fp64 [256][16] with per-row double2 rotation
    //  phase C: Wu staged fp32 [512][18]
    __shared__ double smem_d[4608];
    __shared__ double cn2_d[256];
    __shared__ double zbuf[16][17];
    __shared__ double lred[8];
    float* smf = reinterpret_cast<float*>(smem_d);

    const int t = threadIdx.x;
    const int g = t >> 5;
    const int m = t & 31;
    const int tok0 = blockIdx.x * 16 + g * 2;

    // ---- load residual (fp64) ----
    double res[2][32];
#pragma unroll
    for (int rr = 0; rr < 2; ++rr) {
        const float* zp = z_e + (size_t)(tok0 + rr) * 1024 + m;
#pragma unroll
        for (int j = 0; j < 32; ++j) res[rr][j] = (double)zp[32 * j];
    }

    double acc_loss = 0.0;

    for (int l = 0; l < 8; ++l) {
        // ================= PHASE A: z = res @ Wd[l]^T + bd =================
        double pa[2][16];
#pragma unroll
        for (int rr = 0; rr < 2; ++rr)
#pragma unroll
            for (int c = 0; c < 16; ++c) pa[rr][c] = 0.0;

#pragma unroll
        for (int half = 0; half < 2; ++half) {
            __syncthreads();
            {   // stage Wd (16 x 1024, c-major) -> WdT_s [dloc][c], stride 18
                const int sc = t >> 4;       // 0..15 : c row
                const int sq = t & 15;       // 0..15
                const float* wp = Wd + ((size_t)l * 16 + sc) * 1024
                                  + half * 512 + 4 * sq;
#pragma unroll
                for (int p = 0; p < 8; ++p) {
                    const float4 v = *(const float4*)(wp + p * 64);
                    const int dl = p * 64 + 4 * sq;
                    smf[(dl + 0) * 18 + sc] = v.x;
                    smf[(dl + 1) * 18 + sc] = v.y;
                    smf[(dl + 2) * 18 + sc] = v.z;
                    smf[(dl + 3) * 18 + sc] = v.w;
                }
            }
            __syncthreads();
#pragma unroll
            for (int jj = 0; jj < 16; ++jj) {
                const int j = half * 16 + jj;
                const int base = (m + 32 * jj) * 18;
                float w[16];
#pragma unroll
                for (int cc = 0; cc < 8; ++cc) {
                    const float2 wv = *(const float2*)&smf[base + 2 * cc];
                    w[2 * cc] = wv.x; w[2 * cc + 1] = wv.y;
                }
#pragma unroll
                for (int c = 0; c < 16; ++c) {
                    const double wdv = (double)w[c];
                    pa[0][c] = fma(res[0][j], wdv, pa[0][c]);
                    pa[1][c] = fma(res[1][j], wdv, pa[1][c]);
                }
            }
        }
        // reduce partials over the 32 lanes of each group (fp64, via LDS)
#pragma unroll
        for (int rh = 0; rh < 2; ++rh) {
            __syncthreads();
            if ((g >> 2) == rh) {
                const int gl = g & 3;
#pragma unroll
                for (int rr = 0; rr < 2; ++rr)
#pragma unroll
                    for (int c = 0; c < 16; ++c)
                        smem_d[m * 130 + (gl * 2 + rr) * 16 + c] = pa[rr][c];
            }
            __syncthreads();
            if (t < 128) {
                double s = 0.0;
#pragma unroll
                for (int mm = 0; mm < 32; ++mm) s += smem_d[mm * 130 + t];
                s += (double)bd[l * 16 + (t & 15)];
                zbuf[rh * 8 + (t >> 4)][t & 15] = s;
            }
        }
        __syncthreads();

        // ================= PHASE B: argmin ||zn - cbn_k||^2 =================
        double znd[2][16];
#pragma unroll
        for (int rr = 0; rr < 2; ++rr) {
            double n2 = 0.0;
#pragma unroll
            for (int c = 0; c < 16; ++c) {
                const double v = zbuf[g * 2 + rr][c];
                n2 = fma(v, v, n2);
            }
            const double iv = 1.0 / fmax(sqrt(n2), 1e-12);
#pragma unroll
            for (int c = 0; c < 16; ++c) znd[rr][c] = zbuf[g * 2 + rr][c] * iv;
        }
        double bs0 = 1e300, bs1 = 1e300;
        int bk0 = 0, bk1 = 0;
        const int rot = m & 7;  // row rotation phase, constant per thread
#pragma unroll
        for (int q = 0; q < 4; ++q) {
            __syncthreads();
            {   // normalize 256 codes (one per thread) -> fp64 LDS
                const int k = q * 256 + t;
                const float* cp = cb + ((size_t)l * 1024 + k) * 16;
                const float4 a0 = ((const float4*)cp)[0];
                const float4 a1 = ((const float4*)cp)[1];
                const float4 a2 = ((const float4*)cp)[2];
                const float4 a3 = ((const float4*)cp)[3];
                const float cf[16] = {a0.x,a0.y,a0.z,a0.w, a1.x,a1.y,a1.z,a1.w,
                                      a2.x,a2.y,a2.z,a2.w, a3.x,a3.y,a3.z,a3.w};
                double n = 0.0;
#pragma unroll
                for (int c = 0; c < 16; ++c) {
                    const double v = (double)cf[c];
                    n = fma(v, v, n);
                }
                const double ivc = 1.0 / fmax(sqrt(n), 1e-12);
                double c2 = 0.0;
                double* rowp = &smem_d[t * 16];
#pragma unroll
                for (int p = 0; p < 8; ++p) {
                    const double v0 = (double)cf[2 * p]     * ivc;
                    const double v1 = (double)cf[2 * p + 1] * ivc;
                    const int slot = ((p + t) & 7) * 2;  // bank-spread rotation
                    rowp[slot] = v0; rowp[slot + 1] = v1;
                    c2 = fma(v0, v0, c2); c2 = fma(v1, v1, c2);
                }
                cn2_d[t] = c2;
            }
            __syncthreads();
#pragma unroll
            for (int kk = 0; kk < 8; ++kk) {
                const int kl = m + 32 * kk;
                const int k = q * 256 + kl;
                const double* rowp = &smem_d[kl * 16];
                double dot0 = 0.0, dot1 = 0.0;
#pragma unroll
                for (int p = 0; p < 8; ++p) {
                    const double2 cv = *(const double2*)&rowp[((p + rot) & 7) * 2];
                    dot0 = fma(cv.x, znd[0][2 * p], dot0);
                    dot0 = fma(cv.y, znd[0][2 * p + 1], dot0);
                    dot1 = fma(cv.x, znd[1][2 * p], dot1);
                    dot1 = fma(cv.y, znd[1][2 * p + 1], dot1);
                }
                const double cn2 = cn2_d[kl];
                const double s0 = fma(-2.0, dot0, cn2);
                const double s1 = fma(-2.0, dot1, cn2);
                if (s0 < bs0) { bs0 = s0; bk0 = k; }
                if (s1 < bs1) { bs1 = s1; bk1 = k; }
            }
        }
        // butterfly reduce over 32 lanes; tie-break to lowest k (argmin semantics)
#pragma unroll
        for (int off = 1; off < 32; off <<= 1) {
            const double o0 = __shfl_xor(bs0, off); const int p0 = __shfl_xor(bk0, off);
            if (o0 < bs0 || (o0 == bs0 && p0 < bk0)) { bs0 = o0; bk0 = p0; }
            const double o1 = __shfl_xor(bs1, off); const int p1 = __shfl_xor(bk1, off);
            if (o1 < bs1 || (o1 == bs1 && p1 < bk1)) { bs1 = o1; bk1 = p1; }
        }
        // gather RAW codebook rows (forward value of straight-through output)
        float zq[2][16];
#pragma unroll
        for (int rr = 0; rr < 2; ++rr) {
            const int bki = (rr == 0) ? bk0 : bk1;
            const float4* qp = (const float4*)(cb + ((size_t)l * 1024 + bki) * 16);
            const float4 q0 = qp[0], q1 = qp[1], q2 = qp[2], q3 = qp[3];
            zq[rr][0]=q0.x;  zq[rr][1]=q0.y;  zq[rr][2]=q0.z;  zq[rr][3]=q0.w;
            zq[rr][4]=q1.x;  zq[rr][5]=q1.y;  zq[rr][6]=q1.z;  zq[rr][7]=q1.w;
            zq[rr][8]=q2.x;  zq[rr][9]=q2.y;  zq[rr][10]=q2.z; zq[rr][11]=q2.w;
            zq[rr][12]=q3.x; zq[rr][13]=q3.y; zq[rr][14]=q3.z; zq[rr][15]=q3.w;
        }
        if (m == 0) {
#pragma unroll
            for (int rr = 0; rr < 2; ++rr) {
                const int tok = tok0 + rr;
                double dl_ = 0.0;
#pragma unroll
                for (int c = 0; c < 16; ++c) {
                    const double dd = zbuf[g * 2 + rr][c] - (double)zq[rr][c];
                    dl_ = fma(dd, dd, dl_);
                }
                acc_loss += dl_;
                out1[(size_t)tok * 8 + l] = (float)((rr == 0) ? bk0 : bk1);
                float* op = out0 + (size_t)tok * 128 + l * 16;
                *(float4*)(op + 0)  = make_float4(zq[rr][0],  zq[rr][1],  zq[rr][2],  zq[rr][3]);
                *(float4*)(op + 4)  = make_float4(zq[rr][4],  zq[rr][5],  zq[rr][6],  zq[rr][7]);
                *(float4*)(op + 8)  = make_float4(zq[rr][8],  zq[rr][9],  zq[rr][10], zq[rr][11]);
                *(float4*)(op + 12) = make_float4(zq[rr][12], zq[rr][13], zq[rr][14], zq[rr][15]);
            }
        }
        // ================= PHASE C: res -= zq @ Wu[l]^T + bu =================
#pragma unroll
        for (int half = 0; half < 2; ++half) {
            __syncthreads();
            {   // stage Wu (1024 x 16, d-major) -> [dloc][c], stride 18
                const int su = t & 3;
                const int sk = t >> 2;   // 0..63
#pragma unroll
                for (int p = 0; p < 8; ++p) {
                    const int dl = p * 64 + sk;
                    const float4 v = *(const float4*)(Wu +
                        ((size_t)l * 1024 + half * 512 + dl) * 16 + 4 * su);
                    smf[dl * 18 + 4 * su + 0] = v.x;
                    smf[dl * 18 + 4 * su + 1] = v.y;
                    smf[dl * 18 + 4 * su + 2] = v.z;
                    smf[dl * 18 + 4 * su + 3] = v.w;
                }
            }
            __syncthreads();
#pragma unroll
            for (int jj = 0; jj < 16; ++jj) {
                const int j = half * 16 + jj;
                const int base = (m + 32 * jj) * 18;
                float w[16];
#pragma unroll
                for (int cc = 0; cc < 8; ++cc) {
                    const float2 wv = *(const float2*)&smf[base + 2 * cc];
                    w[2 * cc] = wv.x; w[2 * cc + 1] = wv.y;
                }
                const double bv = (double)bu[(size_t)l * 1024 + m + 32 * j];
                double a0 = bv, a1 = bv;
#pragma unroll
                for (int c = 0; c < 16; ++c) {
                    const double wdv = (double)w[c];
                    a0 = fma((double)zq[0][c], wdv, a0);
                    a1 = fma((double)zq[1][c], wdv, a1);
                }
                res[0][j] -= a0;
                res[1][j] -= a1;
            }
        }
    } // layers

    if (m == 0) lred[g] = acc_loss;
    __syncthreads();
    if (t == 0) {
        double s = 0.0;
#pragma unroll
        for (int i = 0; i < 8; ++i) s += lred[i];
        const float v = (float)(s * (1.0 / 524288.0));  // 1/(N*CD); sum of per-layer means
        atomicAdd(lossp + 0, v);   // commitment_loss
        atomicAdd(lossp + 1, v);   // codebook_loss (same forward value)
    }
}

extern "C" void kernel_launch(void* const* d_in, const int* in_sizes, int n_in,
                              void* d_out, int out_size, void* d_ws, size_t ws_size,
                              hipStream_t stream) {
    (void)in_sizes; (void)n_in; (void)d_ws; (void)ws_size;
    const float* z_e = (const float*)d_in[0];
    const float* Wd  = (const float*)d_in[1];
    const float* bd  = (const float*)d_in[2];
    const float* cb  = (const float*)d_in[3];
    const float* Wu  = (const float*)d_in[4];
    const float* bu  = (const float*)d_in[5];

    float* out0  = (float*)d_out;                       // (8,4096,128)
    float* out1  = out0 + (size_t)8 * 4096 * 128;       // (8,4096,8) codes as float
    float* lossp = out0 + (size_t)out_size - 3;         // commit, cbl, entropy

    rvq_init<<<1, 64, 0, stream>>>(lossp);
    rvq_main<<<2048, NTHREADS, 0, stream>>>(z_e, Wd, bd, cb, Wu, bu,
                                            out0, out1, lossp);
}